// Round 12
// baseline (16.384 us; speedup 1.0000x reference)
//
#include <hip/hip_runtime.h>
#include <cstdint>

#define DIM 64
#define NREL 8
#define IPB 64             // items per block: wave 0 bins them with ONE ballot pass
#define CAP 64             // = IPB: overflow structurally impossible
#define NTHREADS 512       // 8 waves; wave w scores relation w

typedef __attribute__((ext_vector_type(8))) short short8;   // 8 bf16 (4 VGPRs)
typedef __attribute__((ext_vector_type(4))) float f32x4;

__device__ __forceinline__ uint32_t cvtpk_bf16(float lo, float hi) {
    uint32_t r;
    asm("v_cvt_pk_bf16_f32 %0, %1, %2" : "=v"(r) : "v"(lo), "v"(hi));
    return r;                          // [bf16(lo) | bf16(hi)<<16]
}

// ---------------------------------------------------------------------------
// ONE kernel, minimal critical path:
//   - All 8 waves issue their R-fragment (B-side) loads FIRST (independent
//     of binning; L1/L2-hot).
//   - Wave 0 bins the block's 64 items: 3 coalesced idx loads, one ballot
//     pass (rank = popcount below lane), writes dslot + tcnt. ONE barrier.
//   - Wave w scores relation w: descriptor reads (qa + qj) and ALL epilogue
//     n-gathers are issued BEFORE the MFMAs so L3 latency overlaps compute.
// Fragment layouts (learn_hip-verified):
//   A: row = lane&15, k = (lane>>4)*8 + j
//   B: col = lane&15, k = (lane>>4)*8 + j
//   C: col = lane&15, row = (lane>>4)*4 + reg
// ---------------------------------------------------------------------------
__global__ __launch_bounds__(NTHREADS, 4) void fused_kernel(
    const int* __restrict__ node_idx,
    const int* __restrict__ rel_idx,
    const int* __restrict__ nb_idx,
    const float* __restrict__ node_table,
    const float* __restrict__ rel_table,
    float* __restrict__ out, int B)
{
    __shared__ int4 dslot[NREL][CAP];   // 8 KB
    __shared__ int  tcnt[NREL];

    int tid  = threadIdx.x;
    int lane = tid & 63;
    int wv   = tid >> 6;                // wave id 0..7 = relation in phase 2

    int lg = lane >> 4;    // 0..3 : k-group / row-group
    int li = lane & 15;    // 0..15: item (A) / column (B,C)

    // ---- B-fragments for relation wv: issued before the barrier ----------
    const float* Rb = rel_table + ((size_t)wv << 12);
    float g[2][4][8];
#pragma unroll
    for (int kt = 0; kt < 2; ++kt)
#pragma unroll
        for (int nt = 0; nt < 4; ++nt) {
            const float* p = Rb + (size_t)(kt * 32 + lg * 8) * DIM + nt * 16 + li;
#pragma unroll
            for (int j = 0; j < 8; ++j)
                g[kt][nt][j] = p[j * DIM];
        }

    // ---- Phase 1: wave 0 bins the block's 64 items (one ballot pass) -----
    if (wv == 0) {
        int i = blockIdx.x * IPB + lane;
        bool act = i < B;
        int r  = act ? rel_idx[i]  : -1;
        int ni = act ? node_idx[i] : 0;
        int mi = act ? nb_idx[i]   : 0;

        unsigned long long mymask = 0;
#pragma unroll
        for (int rr = 0; rr < NREL; ++rr) {
            unsigned long long mk = __ballot(r == rr);
            if (lane == rr) tcnt[rr] = (int)__popcll(mk);
            if (rr == r) mymask = mk;
        }
        if (act) {
            int rank = (int)__popcll(mymask & ((1ull << lane) - 1ull));
            int4 q; q.x = ni; q.y = mi; q.z = i; q.w = 0;
            dslot[r][rank] = q;
        }
    }

    // finish B-fragment packing while wave 0 bins
    short8 Bf[2][4];
#pragma unroll
    for (int kt = 0; kt < 2; ++kt)
#pragma unroll
        for (int nt = 0; nt < 4; ++nt) {
            union { uint32_t u[4]; short8 s; } f;
            f.u[0] = cvtpk_bf16(g[kt][nt][0], g[kt][nt][1]);
            f.u[1] = cvtpk_bf16(g[kt][nt][2], g[kt][nt][3]);
            f.u[2] = cvtpk_bf16(g[kt][nt][4], g[kt][nt][5]);
            f.u[3] = cvtpk_bf16(g[kt][nt][6], g[kt][nt][7]);
            Bf[kt][nt] = f.s;
        }

    __syncthreads();                    // the only barrier

    // ---- Phase 2: wave wv scores relation wv -----------------------------
    int n = tcnt[wv];
    if (n == 0) return;                 // wave-uniform

#pragma unroll 1
    for (int base = 0; base < n; base += 16) {
        int rem = n - base;
        if (rem > 16) rem = 16;

        // descriptors first (LDS), then ALL global gathers issued up front
        int4 qa = dslot[wv][base + ((li < rem) ? li : (rem - 1))];
        int4 qj[4];
#pragma unroll
        for (int jr = 0; jr < 4; ++jr) {
            int idx = lg * 4 + jr;
            qj[jr] = dslot[wv][base + ((idx < rem) ? idx : (rem - 1))];
        }

        // m-row loads (this lane's A item)
        const float* mrow = node_table + (size_t)qa.x * DIM;
        f32x4 lo0 = *(const f32x4*)(mrow + lg * 8);
        f32x4 hi0 = *(const f32x4*)(mrow + lg * 8 + 4);
        f32x4 lo1 = *(const f32x4*)(mrow + 32 + lg * 8);
        f32x4 hi1 = *(const f32x4*)(mrow + 32 + lg * 8 + 4);

        // n-gathers hoisted BEFORE the MFMAs (overlap L3 latency w/ compute)
        float nval[4][4];               // [jr][nt], statically indexed
#pragma unroll
        for (int jr = 0; jr < 4; ++jr)
#pragma unroll
            for (int nt = 0; nt < 4; ++nt)
                nval[jr][nt] = node_table[(size_t)qj[jr].y * DIM + nt * 16 + li];

        // A-fragments
        short8 Af[2];
        {
            union { uint32_t u[4]; short8 s; } f;
            f.u[0] = cvtpk_bf16(lo0.x, lo0.y);
            f.u[1] = cvtpk_bf16(lo0.z, lo0.w);
            f.u[2] = cvtpk_bf16(hi0.x, hi0.y);
            f.u[3] = cvtpk_bf16(hi0.z, hi0.w);
            Af[0] = f.s;
            f.u[0] = cvtpk_bf16(lo1.x, lo1.y);
            f.u[1] = cvtpk_bf16(lo1.z, lo1.w);
            f.u[2] = cvtpk_bf16(hi1.x, hi1.y);
            f.u[3] = cvtpk_bf16(hi1.z, hi1.w);
            Af[1] = f.s;
        }

        // 8 MFMAs: temp(16x64) = M @ R
        f32x4 acc[4];
#pragma unroll
        for (int nt = 0; nt < 4; ++nt) {
            f32x4 z = {0.f, 0.f, 0.f, 0.f};
            acc[nt] = __builtin_amdgcn_mfma_f32_16x16x32_bf16(Af[0], Bf[0][nt], z, 0, 0, 0);
            acc[nt] = __builtin_amdgcn_mfma_f32_16x16x32_bf16(Af[1], Bf[1][nt], acc[nt], 0, 0, 0);
        }

        // epilogue: rows lg*4+jr; n-values already in registers
        float s0 = 0.f, s1 = 0.f, s2 = 0.f, s3 = 0.f;
#pragma unroll
        for (int nt = 0; nt < 4; ++nt) {
            s0 = fmaf(acc[nt].x, nval[0][nt], s0);
            s1 = fmaf(acc[nt].y, nval[1][nt], s1);
            s2 = fmaf(acc[nt].z, nval[2][nt], s2);
            s3 = fmaf(acc[nt].w, nval[3][nt], s3);
        }
#pragma unroll
        for (int off = 1; off < 16; off <<= 1) {   // reduce over 16 columns
            s0 += __shfl_xor(s0, off, 64);
            s1 += __shfl_xor(s1, off, 64);
            s2 += __shfl_xor(s2, off, 64);
            s3 += __shfl_xor(s3, off, 64);
        }

        if (li == 0) {
            if (lg * 4 + 0 < rem) out[qj[0].z] = 1.0f / (1.0f + __expf(-s0));
            if (lg * 4 + 1 < rem) out[qj[1].z] = 1.0f / (1.0f + __expf(-s1));
            if (lg * 4 + 2 < rem) out[qj[2].z] = 1.0f / (1.0f + __expf(-s2));
            if (lg * 4 + 3 < rem) out[qj[3].z] = 1.0f / (1.0f + __expf(-s3));
        }
    }
}

extern "C" void kernel_launch(void* const* d_in, const int* in_sizes, int n_in,
                              void* d_out, int out_size, void* d_ws, size_t ws_size,
                              hipStream_t stream) {
    const int*   node_idx   = (const int*)d_in[0];
    const int*   rel_idx    = (const int*)d_in[1];
    const int*   nb_idx     = (const int*)d_in[2];
    const float* node_table = (const float*)d_in[3];
    const float* rel_table  = (const float*)d_in[4];
    float* out = (float*)d_out;
    int B = in_sizes[0];   // 65536

    int blocks = (B + IPB - 1) / IPB;   // 1024 -> ~4 blocks/CU
    fused_kernel<<<blocks, NTHREADS, 0, stream>>>(node_idx, rel_idx, nb_idx,
                                                  node_table, rel_table, out, B);
}